// Round 1
// baseline (758.178 us; speedup 1.0000x reference)
//
#include <hip/hip_runtime.h>
#include <stdint.h>

typedef unsigned short u16;
typedef __attribute__((ext_vector_type(8))) short short8;
typedef __attribute__((ext_vector_type(4))) float f32x4;
typedef __attribute__((ext_vector_type(4))) unsigned short u16x4;

#define S_LEN 2048
#define NH 16
#define DMODEL 1024
#define NR 129

#define MFMA(a,b,c) __builtin_amdgcn_mfma_f32_16x16x32_bf16((a),(b),(c),0,0,0)

__device__ __forceinline__ u16 f2bf(float f){
  uint32_t u = __float_as_uint(f);
  u += 0x7fff + ((u >> 16) & 1);
  return (u16)(u >> 16);
}
__device__ __forceinline__ float bf2f(u16 h){ return __uint_as_float(((uint32_t)h) << 16); }

// ---------------- convert X (fp32 -> bf16), 4096x1024 ----------------
__global__ __launch_bounds__(256) void k_convx(const float* __restrict__ X, u16* __restrict__ Xb){
  int i = blockIdx.x * 256 + threadIdx.x;          // 1,048,576 float4s
  const float4* xp = (const float4*)X;
  float4 v = xp[i];
  u16x4 o; o.x = f2bf(v.x); o.y = f2bf(v.y); o.z = f2bf(v.z); o.w = f2bf(v.w);
  *(u16x4*)(Xb + (size_t)i * 4) = o;
}

// ---------------- transpose W[k][n] -> Wt[n][k] bf16, z = q/k/v ----------------
__global__ __launch_bounds__(256) void k_transw(const float* __restrict__ Wq, const float* __restrict__ Wk,
                                                const float* __restrict__ Wv, u16* __restrict__ Wt){
  int z = blockIdx.z;
  const float* W = (z == 0) ? Wq : (z == 1) ? Wk : Wv;
  u16* Ot = Wt + (size_t)z * 1024 * 1024;
  __shared__ float t[64][65];
  int k0 = blockIdx.y * 64, n0 = blockIdx.x * 64;
  int c = threadIdx.x & 63, r0 = (threadIdx.x >> 6) * 16;
  #pragma unroll
  for (int i = 0; i < 16; ++i) t[r0 + i][c] = W[(size_t)(k0 + r0 + i) * 1024 + n0 + c];
  __syncthreads();
  #pragma unroll
  for (int i = 0; i < 16; ++i) Ot[(size_t)(n0 + r0 + i) * 1024 + k0 + c] = f2bf(t[c][r0 + i]);
}

// ---------------- emb_k fp32[129][64] -> bf16[144][64] (zero-padded rows) ----------------
__global__ __launch_bounds__(256) void k_convemb(const float* __restrict__ E, u16* __restrict__ Eb){
  int idx = blockIdx.x * 256 + threadIdx.x;        // 36 blocks -> 9216
  if (idx < 144 * 64){
    int r = idx >> 6;
    Eb[idx] = (r < NR) ? f2bf(E[idx]) : (u16)0;
  }
}

// ---------------- QKV GEMM: [4096,1024] x Wt[1024,1024]^T, bf16 MFMA ----------------
// out layout: [g = b*16+h][s][j] bf16 ; Q pre-scaled by 0.125
__global__ __launch_bounds__(256) void k_qkv(const u16* __restrict__ Xb, const u16* __restrict__ Wt,
                                             const float* __restrict__ bq, const float* __restrict__ bk,
                                             const float* __restrict__ bv,
                                             u16* __restrict__ Qs, u16* __restrict__ Kb, u16* __restrict__ Vb){
  const int z = blockIdx.z;
  const u16* W = Wt + (size_t)z * 1024 * 1024;
  const float* bias = (z == 0) ? bq : (z == 1) ? bk : bv;
  u16* outp = (z == 0) ? Qs : (z == 1) ? Kb : Vb;
  const float vs = (z == 0) ? 0.125f : 1.0f;
  const int n0 = blockIdx.x * 128, m0 = blockIdx.y * 128;
  const int tid = threadIdx.x, w = tid >> 6, lane = tid & 63, l15 = lane & 15, quad = lane >> 4;
  const int wm = (w >> 1) * 64, wn = (w & 1) * 64;
  __shared__ __attribute__((aligned(16))) u16 As[128][40];
  __shared__ __attribute__((aligned(16))) u16 Bs[128][40];
  f32x4 acc[4][4];
  #pragma unroll
  for (int i = 0; i < 4; ++i)
    #pragma unroll
    for (int j = 0; j < 4; ++j) acc[i][j] = (f32x4){0.f,0.f,0.f,0.f};

  for (int k0 = 0; k0 < 1024; k0 += 32){
    __syncthreads();
    #pragma unroll
    for (int i = 0; i < 2; ++i){
      int c = tid + i * 256; int r = c >> 2, ch = (c & 3) * 8;
      *(short8*)&As[r][ch] = *(const short8*)(Xb + (size_t)(m0 + r) * 1024 + k0 + ch);
      *(short8*)&Bs[r][ch] = *(const short8*)(W  + (size_t)(n0 + r) * 1024 + k0 + ch);
    }
    __syncthreads();
    short8 af[4], bfr[4];
    #pragma unroll
    for (int f = 0; f < 4; ++f){
      af[f]  = *(const short8*)&As[wm + f * 16 + l15][quad * 8];
      bfr[f] = *(const short8*)&Bs[wn + f * 16 + l15][quad * 8];
    }
    #pragma unroll
    for (int i = 0; i < 4; ++i)
      #pragma unroll
      for (int j = 0; j < 4; ++j) acc[i][j] = MFMA(af[i], bfr[j], acc[i][j]);
  }
  #pragma unroll
  for (int i = 0; i < 4; ++i){
    #pragma unroll
    for (int j = 0; j < 4; ++j){
      int col = n0 + wn + j * 16 + l15;
      float bsv = bias[col];
      int hh = col >> 6, jd = col & 63;
      #pragma unroll
      for (int r = 0; r < 4; ++r){
        int row = m0 + wm + i * 16 + quad * 4 + r;
        int bb = row >> 11, s = row & 2047;
        float vv = (acc[i][j][r] + bsv) * vs;
        outp[(((size_t)(bb * 16 + hh)) * S_LEN + s) * 64 + jd] = f2bf(vv);
      }
    }
  }
}

// ---------------- transpose V: [g][s][d] -> Vt[g][d][s] ----------------
__global__ __launch_bounds__(256) void k_transv(const u16* __restrict__ Vb, u16* __restrict__ Vt){
  const int g = blockIdx.y; const int s0 = blockIdx.x * 64;
  __shared__ __attribute__((aligned(16))) u16 t[64][72];
  const int tid = threadIdx.x;
  #pragma unroll
  for (int i = 0; i < 2; ++i){
    int c = tid + i * 256; int r = c >> 3, ch = (c & 7) * 8;
    *(short8*)&t[r][ch] = *(const short8*)(Vb + ((size_t)g * S_LEN + s0 + r) * 64 + ch);
  }
  __syncthreads();
  #pragma unroll
  for (int i = 0; i < 2; ++i){
    int c = tid + i * 256; int d = c >> 3, ch = (c & 7) * 8;
    short8 vv;
    #pragma unroll
    for (int u = 0; u < 8; ++u) vv[u] = (short)t[ch + u][d];
    *(short8*)(Vt + ((size_t)g * 64 + d) * S_LEN + s0 + ch) = vv;
  }
}

// ---------------- flash attention: O = softmax(QK^T + qe-gather + mask) V ----------------
// also stores per-row m, l, l_left(=sum exp over k <= q-64)
__global__ __launch_bounds__(256) void k_flash(const u16* __restrict__ QS, const u16* __restrict__ KB,
                                               const u16* __restrict__ VT, const u16* __restrict__ EMBK,
                                               const float* __restrict__ mask, float* __restrict__ out,
                                               float* __restrict__ mS, float* __restrict__ lS,
                                               float* __restrict__ llS){
  const int g = blockIdx.y; const int b = g >> 4; const int h = g & 15;
  const int q0 = blockIdx.x * 64;
  const int tid = threadIdx.x;
  const int w = tid >> 6; const int lane = tid & 63;
  const int l15 = lane & 15; const int quad = lane >> 4;

  __shared__ __attribute__((aligned(16))) u16 Ks[64][72];
  __shared__ __attribute__((aligned(16))) u16 Vs[64][72];
  __shared__ __attribute__((aligned(16))) u16 Ps[4][16][72];
  __shared__ float QE[64][132];

  // Q A-fragments straight from global (rows w*16+l15, dims quad*8.. / 32+quad*8..)
  const u16* qptr = QS + ((size_t)g * S_LEN + q0 + w * 16 + l15) * 64 + quad * 8;
  short8 qa0 = *(const short8*)qptr;
  short8 qa1 = *(const short8*)(qptr + 32);

  const int qlb = w * 16 + quad * 4;   // local C-row base for this lane

  // qe = Q @ emb_k^T  (this wave's 16 rows; cols 0..128)
  #pragma unroll
  for (int fn = 0; fn < 9; ++fn){
    const u16* ep = EMBK + (fn * 16 + l15) * 64 + quad * 8;
    short8 eb0 = *(const short8*)ep;
    short8 eb1 = *(const short8*)(ep + 32);
    f32x4 c = (f32x4){0.f,0.f,0.f,0.f};
    c = MFMA(qa0, eb0, c);
    c = MFMA(qa1, eb1, c);
    int col = fn * 16 + l15;
    if (col < NR){
      #pragma unroll
      for (int r = 0; r < 4; ++r) QE[qlb + r][col] = c[r];
    }
  }

  f32x4 o[4];
  #pragma unroll
  for (int f = 0; f < 4; ++f) o[f] = (f32x4){0.f,0.f,0.f,0.f};
  float m_i[4], l_i[4], ll_i[4];
  #pragma unroll
  for (int r = 0; r < 4; ++r){ m_i[r] = -INFINITY; l_i[r] = 0.f; ll_i[r] = 0.f; }

  for (int kt = 0; kt < S_LEN; kt += 64){
    __syncthreads();
    #pragma unroll
    for (int i = 0; i < 2; ++i){
      int c = tid + i * 256; int row = c >> 3, ch = (c & 7) * 8;
      *(short8*)&Ks[row][ch] = *(const short8*)(KB + ((size_t)g * S_LEN + kt + row) * 64 + ch);
      *(short8*)&Vs[row][ch] = *(const short8*)(VT + ((size_t)g * 64 + row) * S_LEN + kt + ch);
    }
    __syncthreads();

    // scores
    f32x4 sc[4];
    #pragma unroll
    for (int fn = 0; fn < 4; ++fn){
      short8 kb0 = *(const short8*)&Ks[fn * 16 + l15][quad * 8];
      short8 kb1 = *(const short8*)&Ks[fn * 16 + l15][32 + quad * 8];
      f32x4 c = (f32x4){0.f,0.f,0.f,0.f};
      c = MFMA(qa0, kb0, c);
      c = MFMA(qa1, kb1, c);
      sc[fn] = c;
    }
    // relative-key bias gather + mask
    unsigned lm = 0;
    #pragma unroll
    for (int fn = 0; fn < 4; ++fn){
      int kg = kt + fn * 16 + l15;
      float mv = mask[b * S_LEN + kg];
      #pragma unroll
      for (int r = 0; r < 4; ++r){
        int dq = (q0 + qlb + r) - kg + 64;
        int ridx = min(max(dq, 0), 128);
        lm |= (ridx == 128) ? (1u << (fn * 4 + r)) : 0u;
        sc[fn][r] += QE[qlb + r][ridx] + mv;
      }
    }
    // online softmax
    float rx[4];
    #pragma unroll
    for (int r = 0; r < 4; ++r)
      rx[r] = fmaxf(fmaxf(sc[0][r], sc[1][r]), fmaxf(sc[2][r], sc[3][r]));
    #pragma unroll
    for (int st = 1; st < 16; st <<= 1)
      #pragma unroll
      for (int r = 0; r < 4; ++r) rx[r] = fmaxf(rx[r], __shfl_xor(rx[r], st, 64));
    float al[4];
    #pragma unroll
    for (int r = 0; r < 4; ++r){
      float nm = fmaxf(m_i[r], rx[r]);
      al[r] = __expf(m_i[r] - nm);
      m_i[r] = nm;
    }
    float ps[4] = {0.f,0.f,0.f,0.f}, pl[4] = {0.f,0.f,0.f,0.f};
    #pragma unroll
    for (int fn = 0; fn < 4; ++fn)
      #pragma unroll
      for (int r = 0; r < 4; ++r){
        float p = __expf(sc[fn][r] - m_i[r]);
        sc[fn][r] = p;
        ps[r] += p;
        pl[r] += ((lm >> (fn * 4 + r)) & 1u) ? p : 0.f;
      }
    #pragma unroll
    for (int st = 1; st < 16; st <<= 1)
      #pragma unroll
      for (int r = 0; r < 4; ++r){
        ps[r] += __shfl_xor(ps[r], st, 64);
        pl[r] += __shfl_xor(pl[r], st, 64);
      }
    #pragma unroll
    for (int r = 0; r < 4; ++r){
      l_i[r]  = l_i[r]  * al[r] + ps[r];
      ll_i[r] = ll_i[r] * al[r] + pl[r];
    }
    #pragma unroll
    for (int f = 0; f < 4; ++f)
      #pragma unroll
      for (int r = 0; r < 4; ++r) o[f][r] *= al[r];
    // P -> LDS (this wave's private region)
    #pragma unroll
    for (int fn = 0; fn < 4; ++fn)
      #pragma unroll
      for (int r = 0; r < 4; ++r) Ps[w][quad * 4 + r][fn * 16 + l15] = f2bf(sc[fn][r]);
    // PV
    #pragma unroll
    for (int ks = 0; ks < 2; ++ks){
      short8 pa = *(const short8*)&Ps[w][l15][ks * 32 + quad * 8];
      #pragma unroll
      for (int fd = 0; fd < 4; ++fd){
        short8 vb = *(const short8*)&Vs[fd * 16 + l15][ks * 32 + quad * 8];
        o[fd] = MFMA(pa, vb, o[fd]);
      }
    }
  }

  float inv[4];
  #pragma unroll
  for (int r = 0; r < 4; ++r) inv[r] = 1.f / l_i[r];
  #pragma unroll
  for (int fd = 0; fd < 4; ++fd)
    #pragma unroll
    for (int r = 0; r < 4; ++r){
      int row = q0 + qlb + r;
      out[((size_t)(b * S_LEN + row)) * DMODEL + h * 64 + fd * 16 + l15] = o[fd][r] * inv[r];
    }
  if (l15 == 0){
    #pragma unroll
    for (int r = 0; r < 4; ++r){
      int idx = g * S_LEN + q0 + qlb + r;
      mS[idx] = m_i[r]; lS[idx] = l_i[r]; llS[idx] = ll_i[r];
    }
  }
}

// ---------------- band + tails: add rel_v contribution into out ----------------
__global__ __launch_bounds__(256) void k_band(const u16* __restrict__ QS, const u16* __restrict__ KB,
                                              const float* __restrict__ embk, const float* __restrict__ embv,
                                              const float* __restrict__ mask,
                                              const float* __restrict__ mS, const float* __restrict__ lS,
                                              const float* __restrict__ llS, float* __restrict__ out){
  const int g = blockIdx.y; const int b = g >> 4; const int h = g & 15;
  const int tid = threadIdx.x;
  const int rl = tid >> 7;             // row 0/1
  const int j  = tid & 127;
  const int q  = blockIdx.x * 2 + rl;
  __shared__ float qrow[2][64];
  __shared__ float bandp[2][128];
  __shared__ float tl[2], tr[2];
  __shared__ float part[2][2];
  __shared__ float hsum[2][64];

  if (j < 64) qrow[rl][j] = bf2f(QS[((size_t)g * S_LEN + q) * 64 + j]);
  __syncthreads();

  float rowm = mS[g * S_LEN + q];
  float invl = 1.f / lS[g * S_LEN + q];
  int k = q - 63 + j;
  float p = 0.f;
  if (j < 127 && k >= 0 && k < S_LEN){
    const u16x4* kp = (const u16x4*)(KB + ((size_t)g * S_LEN + k) * 64);
    const float4* ep = (const float4*)(embk + (size_t)(127 - j) * 64);
    const float4* qp = (const float4*)qrow[rl];
    float s = 0.f;
    #pragma unroll
    for (int d4 = 0; d4 < 16; ++d4){
      u16x4 kv = kp[d4]; float4 e = ep[d4]; float4 qv = qp[d4];
      s += qv.x * (bf2f(kv.x) + e.x) + qv.y * (bf2f(kv.y) + e.y)
         + qv.z * (bf2f(kv.z) + e.z) + qv.w * (bf2f(kv.w) + e.w);
    }
    s += mask[b * S_LEN + k];
    p = __expf(s - rowm) * invl;
  }
  bandp[rl][j] = p;
  float v = p;
  #pragma unroll
  for (int st = 1; st < 64; st <<= 1) v += __shfl_xor(v, st, 64);
  if ((tid & 63) == 0) part[rl][(tid >> 6) & 1] = v;
  __syncthreads();
  if (j == 0){
    float bs = part[rl][0] + part[rl][1];
    float tleft = llS[g * S_LEN + q] * invl;
    tl[rl] = tleft;
    tr[rl] = 1.f - tleft - bs;
  }
  __syncthreads();
  int dim = tid & 63; int half = (tid >> 6) & 1;
  float acc = 0.f;
  for (int jj = half * 64; jj < half * 64 + 64; ++jj)
    acc += bandp[rl][jj] * embv[(size_t)(127 - jj) * 64 + dim];
  if (half == 1) hsum[rl][dim] = acc;
  __syncthreads();
  if (half == 0){
    float tot = acc + hsum[rl][dim] + tl[rl] * embv[128 * 64 + dim] + tr[rl] * embv[dim];
    out[((size_t)(b * S_LEN + q)) * DMODEL + h * 64 + dim] += tot;
  }
}

extern "C" void kernel_launch(void* const* d_in, const int* in_sizes, int n_in,
                              void* d_out, int out_size, void* d_ws, size_t ws_size,
                              hipStream_t stream){
  const float* X    = (const float*)d_in[0];
  const float* mask = (const float*)d_in[1];
  const float* Wq   = (const float*)d_in[2];
  const float* bq   = (const float*)d_in[3];
  const float* Wk   = (const float*)d_in[4];
  const float* bk   = (const float*)d_in[5];
  const float* Wv   = (const float*)d_in[6];
  const float* bv   = (const float*)d_in[7];
  const float* embk = (const float*)d_in[8];
  const float* embv = (const float*)d_in[9];
  float* out = (float*)d_out;
  char* ws = (char*)d_ws;

  u16* XB  = (u16*)(ws + 0);            // 8,388,608
  u16* WT  = (u16*)(ws + 8388608);      // 6,291,456
  u16* EKB = (u16*)(ws + 14680064);     // 18,432
  u16* QS  = (u16*)(ws + 14698496);     // 8,388,608
  u16* KB  = (u16*)(ws + 23087104);     // 8,388,608
  u16* VB  = (u16*)(ws + 31475712);     // 8,388,608
  u16* VT  = (u16*)(ws + 39864320);     // 8,388,608
  float* MS  = (float*)(ws + 48252928); // 262,144
  float* LS  = (float*)(ws + 48515072); // 262,144
  float* LLS = (float*)(ws + 48777216); // 262,144  (end 49,039,360)

  k_convx  <<<4096, 256, 0, stream>>>(X, XB);
  k_transw <<<dim3(16, 16, 3), 256, 0, stream>>>(Wq, Wk, Wv, WT);
  k_convemb<<<36, 256, 0, stream>>>(embk, EKB);
  k_qkv    <<<dim3(8, 32, 3), 256, 0, stream>>>(XB, WT, bq, bk, bv, QS, KB, VB);
  k_transv <<<dim3(32, 32), 256, 0, stream>>>(VB, VT);
  k_flash  <<<dim3(32, 32), 256, 0, stream>>>(QS, KB, VT, EKB, mask, out, MS, LS, LLS);
  k_band   <<<dim3(1024, 32), 256, 0, stream>>>(QS, KB, embk, embv, mask, MS, LS, LLS, out);
}

// Round 2
// 383.620 us; speedup vs baseline: 1.9764x; 1.9764x over previous
//
#include <hip/hip_runtime.h>
#include <stdint.h>

typedef unsigned short u16;
typedef __attribute__((ext_vector_type(8))) short short8;
typedef __attribute__((ext_vector_type(4))) float f32x4;
typedef __attribute__((ext_vector_type(4))) unsigned short u16x4;

#define S_LEN 2048
#define NH 16
#define DMODEL 1024
#define NR 129

#define MFMA(a,b,c) __builtin_amdgcn_mfma_f32_16x16x32_bf16((a),(b),(c),0,0,0)

__device__ __forceinline__ u16 f2bf(float f){
  uint32_t u = __float_as_uint(f);
  u += 0x7fff + ((u >> 16) & 1);
  return (u16)(u >> 16);
}
__device__ __forceinline__ float bf2f(u16 h){ return __uint_as_float(((uint32_t)h) << 16); }

// ---------------- convert X (fp32 -> bf16), 4096x1024 ----------------
__global__ __launch_bounds__(256) void k_convx(const float* __restrict__ X, u16* __restrict__ Xb){
  int i = blockIdx.x * 256 + threadIdx.x;          // 1,048,576 float4s
  const float4* xp = (const float4*)X;
  float4 v = xp[i];
  u16x4 o; o.x = f2bf(v.x); o.y = f2bf(v.y); o.z = f2bf(v.z); o.w = f2bf(v.w);
  *(u16x4*)(Xb + (size_t)i * 4) = o;
}

// ---------------- transpose W[k][n] -> Wt[n][k] bf16, z = q/k/v ----------------
__global__ __launch_bounds__(256) void k_transw(const float* __restrict__ Wq, const float* __restrict__ Wk,
                                                const float* __restrict__ Wv, u16* __restrict__ Wt){
  int z = blockIdx.z;
  const float* W = (z == 0) ? Wq : (z == 1) ? Wk : Wv;
  u16* Ot = Wt + (size_t)z * 1024 * 1024;
  __shared__ float t[64][65];
  int k0 = blockIdx.y * 64, n0 = blockIdx.x * 64;
  int c = threadIdx.x & 63, r0 = (threadIdx.x >> 6) * 16;
  #pragma unroll
  for (int i = 0; i < 16; ++i) t[r0 + i][c] = W[(size_t)(k0 + r0 + i) * 1024 + n0 + c];
  __syncthreads();
  #pragma unroll
  for (int i = 0; i < 16; ++i) Ot[(size_t)(n0 + r0 + i) * 1024 + k0 + c] = f2bf(t[c][r0 + i]);
}

// ---------------- emb_k fp32[129][64] -> bf16[144][64] (zero-padded rows) ----------------
__global__ __launch_bounds__(256) void k_convemb(const float* __restrict__ E, u16* __restrict__ Eb){
  int idx = blockIdx.x * 256 + threadIdx.x;        // 36 blocks -> 9216
  if (idx < 144 * 64){
    int r = idx >> 6;
    Eb[idx] = (r < NR) ? f2bf(E[idx]) : (u16)0;
  }
}

// ---------------- QKV GEMM: [4096,1024] x Wt[1024,1024]^T, bf16 MFMA ----------------
// out layout: [g = b*16+h][s][j] bf16 ; Q pre-scaled by 0.125
__global__ __launch_bounds__(256) void k_qkv(const u16* __restrict__ Xb, const u16* __restrict__ Wt,
                                             const float* __restrict__ bq, const float* __restrict__ bk,
                                             const float* __restrict__ bv,
                                             u16* __restrict__ Qs, u16* __restrict__ Kb, u16* __restrict__ Vb){
  const int z = blockIdx.z;
  const u16* W = Wt + (size_t)z * 1024 * 1024;
  const float* bias = (z == 0) ? bq : (z == 1) ? bk : bv;
  u16* outp = (z == 0) ? Qs : (z == 1) ? Kb : Vb;
  const float vs = (z == 0) ? 0.125f : 1.0f;
  const int n0 = blockIdx.x * 128, m0 = blockIdx.y * 128;
  const int tid = threadIdx.x, w = tid >> 6, lane = tid & 63, l15 = lane & 15, quad = lane >> 4;
  const int wm = (w >> 1) * 64, wn = (w & 1) * 64;
  __shared__ __attribute__((aligned(16))) u16 As[128][40];
  __shared__ __attribute__((aligned(16))) u16 Bs[128][40];
  f32x4 acc[4][4];
  #pragma unroll
  for (int i = 0; i < 4; ++i)
    #pragma unroll
    for (int j = 0; j < 4; ++j) acc[i][j] = (f32x4){0.f,0.f,0.f,0.f};

  for (int k0 = 0; k0 < 1024; k0 += 32){
    __syncthreads();
    #pragma unroll
    for (int i = 0; i < 2; ++i){
      int c = tid + i * 256; int r = c >> 2, ch = (c & 3) * 8;
      *(short8*)&As[r][ch] = *(const short8*)(Xb + (size_t)(m0 + r) * 1024 + k0 + ch);
      *(short8*)&Bs[r][ch] = *(const short8*)(W  + (size_t)(n0 + r) * 1024 + k0 + ch);
    }
    __syncthreads();
    short8 af[4], bfr[4];
    #pragma unroll
    for (int f = 0; f < 4; ++f){
      af[f]  = *(const short8*)&As[wm + f * 16 + l15][quad * 8];
      bfr[f] = *(const short8*)&Bs[wn + f * 16 + l15][quad * 8];
    }
    #pragma unroll
    for (int i = 0; i < 4; ++i)
      #pragma unroll
      for (int j = 0; j < 4; ++j) acc[i][j] = MFMA(af[i], bfr[j], acc[i][j]);
  }
  #pragma unroll
  for (int i = 0; i < 4; ++i){
    #pragma unroll
    for (int j = 0; j < 4; ++j){
      int col = n0 + wn + j * 16 + l15;
      float bsv = bias[col];
      int hh = col >> 6, jd = col & 63;
      #pragma unroll
      for (int r = 0; r < 4; ++r){
        int row = m0 + wm + i * 16 + quad * 4 + r;
        int bb = row >> 11, s = row & 2047;
        float vv = (acc[i][j][r] + bsv) * vs;
        outp[(((size_t)(bb * 16 + hh)) * S_LEN + s) * 64 + jd] = f2bf(vv);
      }
    }
  }
}

// ---------------- transpose V: [g][s][d] -> Vt[g][d][s] ----------------
__global__ __launch_bounds__(256) void k_transv(const u16* __restrict__ Vb, u16* __restrict__ Vt){
  const int g = blockIdx.y; const int s0 = blockIdx.x * 64;
  __shared__ __attribute__((aligned(16))) u16 t[64][72];
  const int tid = threadIdx.x;
  #pragma unroll
  for (int i = 0; i < 2; ++i){
    int c = tid + i * 256; int r = c >> 3, ch = (c & 7) * 8;
    *(short8*)&t[r][ch] = *(const short8*)(Vb + ((size_t)g * S_LEN + s0 + r) * 64 + ch);
  }
  __syncthreads();
  #pragma unroll
  for (int i = 0; i < 2; ++i){
    int c = tid + i * 256; int d = c >> 3, ch = (c & 7) * 8;
    short8 vv;
    #pragma unroll
    for (int u = 0; u < 8; ++u) vv[u] = (short)t[ch + u][d];
    *(short8*)(Vt + ((size_t)g * 64 + d) * S_LEN + s0 + ch) = vv;
  }
}

// ---------------- flash attention: O = softmax(QK^T + qe-gather + mask) V ----------------
// also stores per-row m, l, l_left(=sum exp over k <= q-64)
__global__ __launch_bounds__(256) void k_flash(const u16* __restrict__ QS, const u16* __restrict__ KB,
                                               const u16* __restrict__ VT, const u16* __restrict__ EMBK,
                                               const float* __restrict__ mask, float* __restrict__ out,
                                               float* __restrict__ mS, float* __restrict__ lS,
                                               float* __restrict__ llS){
  const int g = blockIdx.y; const int b = g >> 4; const int h = g & 15;
  const int q0 = blockIdx.x * 64;
  const int tid = threadIdx.x;
  const int w = tid >> 6; const int lane = tid & 63;
  const int l15 = lane & 15; const int quad = lane >> 4;

  __shared__ __attribute__((aligned(16))) u16 Ks[64][72];
  __shared__ __attribute__((aligned(16))) u16 Vs[64][72];
  __shared__ __attribute__((aligned(16))) u16 Ps[4][16][72];
  __shared__ float QE[64][132];

  // Q A-fragments straight from global (rows w*16+l15, dims quad*8.. / 32+quad*8..)
  const u16* qptr = QS + ((size_t)g * S_LEN + q0 + w * 16 + l15) * 64 + quad * 8;
  short8 qa0 = *(const short8*)qptr;
  short8 qa1 = *(const short8*)(qptr + 32);

  const int qlb = w * 16 + quad * 4;   // local C-row base for this lane

  // qe = Q @ emb_k^T  (this wave's 16 rows; cols 0..128)
  #pragma unroll
  for (int fn = 0; fn < 9; ++fn){
    const u16* ep = EMBK + (fn * 16 + l15) * 64 + quad * 8;
    short8 eb0 = *(const short8*)ep;
    short8 eb1 = *(const short8*)(ep + 32);
    f32x4 c = (f32x4){0.f,0.f,0.f,0.f};
    c = MFMA(qa0, eb0, c);
    c = MFMA(qa1, eb1, c);
    int col = fn * 16 + l15;
    if (col < NR){
      #pragma unroll
      for (int r = 0; r < 4; ++r) QE[qlb + r][col] = c[r];
    }
  }

  f32x4 o[4];
  #pragma unroll
  for (int f = 0; f < 4; ++f) o[f] = (f32x4){0.f,0.f,0.f,0.f};
  float m_i[4], l_i[4], ll_i[4];
  #pragma unroll
  for (int r = 0; r < 4; ++r){ m_i[r] = -INFINITY; l_i[r] = 0.f; ll_i[r] = 0.f; }

  for (int kt = 0; kt < S_LEN; kt += 64){
    __syncthreads();
    #pragma unroll
    for (int i = 0; i < 2; ++i){
      int c = tid + i * 256; int row = c >> 3, ch = (c & 7) * 8;
      *(short8*)&Ks[row][ch] = *(const short8*)(KB + ((size_t)g * S_LEN + kt + row) * 64 + ch);
      *(short8*)&Vs[row][ch] = *(const short8*)(VT + ((size_t)g * 64 + row) * S_LEN + kt + ch);
    }
    __syncthreads();

    // scores
    f32x4 sc[4];
    #pragma unroll
    for (int fn = 0; fn < 4; ++fn){
      short8 kb0 = *(const short8*)&Ks[fn * 16 + l15][quad * 8];
      short8 kb1 = *(const short8*)&Ks[fn * 16 + l15][32 + quad * 8];
      f32x4 c = (f32x4){0.f,0.f,0.f,0.f};
      c = MFMA(qa0, kb0, c);
      c = MFMA(qa1, kb1, c);
      sc[fn] = c;
    }
    // relative-key bias gather + mask
    unsigned lm = 0;
    #pragma unroll
    for (int fn = 0; fn < 4; ++fn){
      int kg = kt + fn * 16 + l15;
      float mv = mask[b * S_LEN + kg];
      #pragma unroll
      for (int r = 0; r < 4; ++r){
        int dq = (q0 + qlb + r) - kg + 64;
        int ridx = min(max(dq, 0), 128);
        lm |= (ridx == 128) ? (1u << (fn * 4 + r)) : 0u;
        sc[fn][r] += QE[qlb + r][ridx] + mv;
      }
    }
    // online softmax
    float rx[4];
    #pragma unroll
    for (int r = 0; r < 4; ++r)
      rx[r] = fmaxf(fmaxf(sc[0][r], sc[1][r]), fmaxf(sc[2][r], sc[3][r]));
    #pragma unroll
    for (int st = 1; st < 16; st <<= 1)
      #pragma unroll
      for (int r = 0; r < 4; ++r) rx[r] = fmaxf(rx[r], __shfl_xor(rx[r], st, 64));
    float al[4];
    #pragma unroll
    for (int r = 0; r < 4; ++r){
      float nm = fmaxf(m_i[r], rx[r]);
      al[r] = __expf(m_i[r] - nm);
      m_i[r] = nm;
    }
    float ps[4] = {0.f,0.f,0.f,0.f}, pl[4] = {0.f,0.f,0.f,0.f};
    #pragma unroll
    for (int fn = 0; fn < 4; ++fn)
      #pragma unroll
      for (int r = 0; r < 4; ++r){
        float p = __expf(sc[fn][r] - m_i[r]);
        sc[fn][r] = p;
        ps[r] += p;
        pl[r] += ((lm >> (fn * 4 + r)) & 1u) ? p : 0.f;
      }
    #pragma unroll
    for (int st = 1; st < 16; st <<= 1)
      #pragma unroll
      for (int r = 0; r < 4; ++r){
        ps[r] += __shfl_xor(ps[r], st, 64);
        pl[r] += __shfl_xor(pl[r], st, 64);
      }
    #pragma unroll
    for (int r = 0; r < 4; ++r){
      l_i[r]  = l_i[r]  * al[r] + ps[r];
      ll_i[r] = ll_i[r] * al[r] + pl[r];
    }
    #pragma unroll
    for (int f = 0; f < 4; ++f)
      #pragma unroll
      for (int r = 0; r < 4; ++r) o[f][r] *= al[r];
    // P -> LDS (this wave's private region)
    #pragma unroll
    for (int fn = 0; fn < 4; ++fn)
      #pragma unroll
      for (int r = 0; r < 4; ++r) Ps[w][quad * 4 + r][fn * 16 + l15] = f2bf(sc[fn][r]);
    // PV
    #pragma unroll
    for (int ks = 0; ks < 2; ++ks){
      short8 pa = *(const short8*)&Ps[w][l15][ks * 32 + quad * 8];
      #pragma unroll
      for (int fd = 0; fd < 4; ++fd){
        short8 vb = *(const short8*)&Vs[fd * 16 + l15][ks * 32 + quad * 8];
        o[fd] = MFMA(pa, vb, o[fd]);
      }
    }
  }

  float inv[4];
  #pragma unroll
  for (int r = 0; r < 4; ++r) inv[r] = 1.f / l_i[r];
  #pragma unroll
  for (int fd = 0; fd < 4; ++fd)
    #pragma unroll
    for (int r = 0; r < 4; ++r){
      int row = q0 + qlb + r;
      out[((size_t)(b * S_LEN + row)) * DMODEL + h * 64 + fd * 16 + l15] = o[fd][r] * inv[r];
    }
  if (l15 == 0){
    #pragma unroll
    for (int r = 0; r < 4; ++r){
      int idx = g * S_LEN + q0 + qlb + r;
      mS[idx] = m_i[r]; lS[idx] = l_i[r]; llS[idx] = ll_i[r];
    }
  }
}

// ---------------- band v2 (MFMA): rel_v contribution via diagonal-band GEMM ----------------
// Per block: 64 q-rows of one (b,h). Recompute band scores S=Q@K^T (+qe+mask) with the
// same MFMA chain as flash, p=exp(s-m)/l, scatter shifted into Pd[row][t], then
// rv = Pd(64x128) @ Ev'(128x64) where Ev'[t]=emb_v[127-t]; tails added in epilogue.
__global__ __launch_bounds__(256) void k_band2(const u16* __restrict__ QS, const u16* __restrict__ KB,
                                               const u16* __restrict__ EMBK, const float* __restrict__ embv,
                                               const float* __restrict__ mask,
                                               const float* __restrict__ mS, const float* __restrict__ lS,
                                               const float* __restrict__ llS, float* __restrict__ out){
  const int g = blockIdx.y; const int b = g >> 4; const int h = g & 15;
  const int q0 = blockIdx.x * 64;
  const int tid = threadIdx.x;
  const int w = tid >> 6; const int lane = tid & 63;
  const int l15 = lane & 15; const int quad = lane >> 4;
  const int wm = w * 16;

  __shared__ union {
    __attribute__((aligned(16))) u16 Ks[192][72];   // K rows q0-63 .. q0+128 (c=0..191, k=q0-63+c)
    __attribute__((aligned(16))) u16 Evs[64][136];  // Evs[d][t] = emb_v[127-t][d], t<=126; else 0
  } uKE;
  __shared__ __attribute__((aligned(16))) u16 Ps[64][136];   // Pd[row][t]
  __shared__ u16 QEs[64][128];                               // qe[row][ridx-1], ridx=1..128

  // zero Ps (tail cols / out-of-band stay 0)
  for (int i = tid; i < 64 * 136 / 2; i += 256) ((uint32_t*)Ps)[i] = 0u;

  // stage K band range: c=0..191 -> k=q0-63+c, zero-fill OOB
  #pragma unroll
  for (int i = 0; i < 6; ++i){
    int c = tid + i * 256; int row = c >> 3, ch = (c & 7) * 8;
    int k = q0 - 63 + row;
    short8 vv;
    if (k >= 0 && k < S_LEN) vv = *(const short8*)(KB + ((size_t)g * S_LEN + k) * 64 + ch);
    else vv = (short8){0,0,0,0,0,0,0,0};
    *(short8*)&uKE.Ks[row][ch] = vv;
  }

  // Q A-fragments (rows wm+l15)
  const u16* qptr = QS + ((size_t)g * S_LEN + q0 + wm + l15) * 64 + quad * 8;
  short8 qa0 = *(const short8*)qptr;
  short8 qa1 = *(const short8*)(qptr + 32);

  __syncthreads();

  // qe = Q @ emb_k^T for this wave's rows; store bf16 at QEs[row][e-1], e=1..128
  #pragma unroll
  for (int fn = 0; fn < 9; ++fn){
    const u16* ep = EMBK + (fn * 16 + l15) * 64 + quad * 8;
    short8 eb0 = *(const short8*)ep;
    short8 eb1 = *(const short8*)(ep + 32);
    f32x4 c = (f32x4){0.f,0.f,0.f,0.f};
    c = MFMA(qa0, eb0, c);
    c = MFMA(qa1, eb1, c);
    int e = fn * 16 + l15;
    if (e >= 1 && e <= 128){
      #pragma unroll
      for (int r = 0; r < 4; ++r) QEs[wm + quad * 4 + r][e - 1] = f2bf(c[r]);
    }
  }

  // band scores: S = Q @ K^T over 192 cols
  f32x4 sc[12];
  #pragma unroll
  for (int cf = 0; cf < 12; ++cf){
    short8 kb0 = *(const short8*)&uKE.Ks[cf * 16 + l15][quad * 8];
    short8 kb1 = *(const short8*)&uKE.Ks[cf * 16 + l15][32 + quad * 8];
    f32x4 c = (f32x4){0.f,0.f,0.f,0.f};
    c = MFMA(qa0, kb0, c);
    c = MFMA(qa1, kb1, c);
    sc[cf] = c;
  }

  __syncthreads();   // Ks reads done; safe to overwrite with Evs

  // build Evs (union with Ks): Evs[d][t] = emb_v[127-t][d] for t<=126, else 0
  #pragma unroll
  for (int it = 0; it < 34; ++it){
    int t = (tid >> 6) + it * 4;
    int d = tid & 63;
    float v = (t <= 126) ? embv[(size_t)(127 - t) * 64 + d] : 0.f;
    uKE.Evs[d][t] = f2bf(v);
  }

  // per-row softmax stats from flash
  float mrow[4], invl[4], tl[4];
  #pragma unroll
  for (int r = 0; r < 4; ++r){
    int idx = g * S_LEN + q0 + wm + quad * 4 + r;
    mrow[r] = mS[idx];
    invl[r] = 1.f / lS[idx];
    tl[r]   = llS[idx] * invl[r];
  }

  // p = exp(s + qe + mask - m)/l ; scatter band into Ps[row][t], t=c-rq
  float rs[4] = {0.f,0.f,0.f,0.f};
  #pragma unroll
  for (int cf = 0; cf < 12; ++cf){
    int c = cf * 16 + l15;
    int k = q0 - 63 + c;
    int kcl = min(max(k, 0), S_LEN - 1);
    float mv = mask[b * S_LEN + kcl];
    #pragma unroll
    for (int r = 0; r < 4; ++r){
      int rq = wm + quad * 4 + r;
      int t = c - rq;
      bool valid = (t >= 0) && (t <= 126) && (k >= 0) && (k < S_LEN);
      if (valid){
        float s = sc[cf][r] + bf2f(QEs[rq][126 - t]) + mv;
        float p = __expf(s - mrow[r]) * invl[r];
        Ps[rq][t] = f2bf(p);
        rs[r] += p;
      }
    }
  }
  // row band-sums across l15 lanes
  #pragma unroll
  for (int st = 1; st < 16; st <<= 1)
    #pragma unroll
    for (int r = 0; r < 4; ++r) rs[r] += __shfl_xor(rs[r], st, 64);

  __syncthreads();   // Ps + Evs ready

  // rv = Pd @ Ev'
  f32x4 o[4];
  #pragma unroll
  for (int f = 0; f < 4; ++f) o[f] = (f32x4){0.f,0.f,0.f,0.f};
  #pragma unroll
  for (int kb = 0; kb < 4; ++kb){
    short8 pa = *(const short8*)&Ps[wm + l15][kb * 32 + quad * 8];
    #pragma unroll
    for (int fd = 0; fd < 4; ++fd){
      short8 vb = *(const short8*)&uKE.Evs[fd * 16 + l15][kb * 32 + quad * 8];
      o[fd] = MFMA(pa, vb, o[fd]);
    }
  }

  // epilogue: add tails and accumulate into out
  #pragma unroll
  for (int fd = 0; fd < 4; ++fd){
    int dim = fd * 16 + l15;
    float evL = embv[(size_t)128 * 64 + dim];   // ridx=128 (k <= q-64)
    float evR = embv[dim];                      // ridx=0   (k >= q+64)
    #pragma unroll
    for (int r = 0; r < 4; ++r){
      float trr = 1.f - tl[r] - rs[r];
      float add = o[fd][r] + tl[r] * evL + trr * evR;
      int row = q0 + wm + quad * 4 + r;
      out[((size_t)(b * S_LEN + row)) * DMODEL + h * 64 + dim] += add;
    }
  }
}

extern "C" void kernel_launch(void* const* d_in, const int* in_sizes, int n_in,
                              void* d_out, int out_size, void* d_ws, size_t ws_size,
                              hipStream_t stream){
  const float* X    = (const float*)d_in[0];
  const float* mask = (const float*)d_in[1];
  const float* Wq   = (const float*)d_in[2];
  const float* bq   = (const float*)d_in[3];
  const float* Wk   = (const float*)d_in[4];
  const float* bk   = (const float*)d_in[5];
  const float* Wv   = (const float*)d_in[6];
  const float* bv   = (const float*)d_in[7];
  const float* embk = (const float*)d_in[8];
  const float* embv = (const float*)d_in[9];
  float* out = (float*)d_out;
  char* ws = (char*)d_ws;

  u16* XB  = (u16*)(ws + 0);            // 8,388,608
  u16* WT  = (u16*)(ws + 8388608);      // 6,291,456
  u16* EKB = (u16*)(ws + 14680064);     // 18,432
  u16* QS  = (u16*)(ws + 14698496);     // 8,388,608
  u16* KB  = (u16*)(ws + 23087104);     // 8,388,608
  u16* VB  = (u16*)(ws + 31475712);     // 8,388,608
  u16* VT  = (u16*)(ws + 39864320);     // 8,388,608
  float* MS  = (float*)(ws + 48252928); // 262,144
  float* LS  = (float*)(ws + 48515072); // 262,144
  float* LLS = (float*)(ws + 48777216); // 262,144  (end 49,039,360)

  k_convx  <<<4096, 256, 0, stream>>>(X, XB);
  k_transw <<<dim3(16, 16, 3), 256, 0, stream>>>(Wq, Wk, Wv, WT);
  k_convemb<<<36, 256, 0, stream>>>(embk, EKB);
  k_qkv    <<<dim3(8, 32, 3), 256, 0, stream>>>(XB, WT, bq, bk, bv, QS, KB, VB);
  k_transv <<<dim3(32, 32), 256, 0, stream>>>(VB, VT);
  k_flash  <<<dim3(32, 32), 256, 0, stream>>>(QS, KB, VT, EKB, mask, out, MS, LS, LLS);
  k_band2  <<<dim3(32, 32), 256, 0, stream>>>(QS, KB, EKB, embv, mask, MS, LS, LLS, out);
}

// Round 3
// 303.219 us; speedup vs baseline: 2.5004x; 1.2652x over previous
//
#include <hip/hip_runtime.h>
#include <stdint.h>

typedef unsigned short u16;
typedef __attribute__((ext_vector_type(8))) short short8;
typedef __attribute__((ext_vector_type(4))) float f32x4;
typedef __attribute__((ext_vector_type(4))) unsigned short u16x4;

#define S_LEN 2048
#define NH 16
#define DMODEL 1024
#define NR 129
#define LOG2E 1.44269504f

#define MFMA(a,b,c) __builtin_amdgcn_mfma_f32_16x16x32_bf16((a),(b),(c),0,0,0)

__device__ __forceinline__ u16 f2bf(float f){
  uint32_t u = __float_as_uint(f);
  u += 0x7fff + ((u >> 16) & 1);
  return (u16)(u >> 16);
}
__device__ __forceinline__ float bf2f(u16 h){ return __uint_as_float(((uint32_t)h) << 16); }

// ---------------- convert X (fp32 -> bf16), 4096x1024 ----------------
__global__ __launch_bounds__(256) void k_convx(const float* __restrict__ X, u16* __restrict__ Xb){
  int i = blockIdx.x * 256 + threadIdx.x;          // 1,048,576 float4s
  const float4* xp = (const float4*)X;
  float4 v = xp[i];
  u16x4 o; o.x = f2bf(v.x); o.y = f2bf(v.y); o.z = f2bf(v.z); o.w = f2bf(v.w);
  *(u16x4*)(Xb + (size_t)i * 4) = o;
}

// ---------------- transpose W[k][n] -> Wt[n][k] bf16, z = q/k/v ----------------
__global__ __launch_bounds__(256) void k_transw(const float* __restrict__ Wq, const float* __restrict__ Wk,
                                                const float* __restrict__ Wv, u16* __restrict__ Wt){
  int z = blockIdx.z;
  const float* W = (z == 0) ? Wq : (z == 1) ? Wk : Wv;
  u16* Ot = Wt + (size_t)z * 1024 * 1024;
  __shared__ float t[64][65];
  int k0 = blockIdx.y * 64, n0 = blockIdx.x * 64;
  int c = threadIdx.x & 63, r0 = (threadIdx.x >> 6) * 16;
  #pragma unroll
  for (int i = 0; i < 16; ++i) t[r0 + i][c] = W[(size_t)(k0 + r0 + i) * 1024 + n0 + c];
  __syncthreads();
  #pragma unroll
  for (int i = 0; i < 16; ++i) Ot[(size_t)(n0 + r0 + i) * 1024 + k0 + c] = f2bf(t[c][r0 + i]);
}

// ---------------- emb_k fp32[129][64] -> bf16[144][64] (zero-padded rows) ----------------
__global__ __launch_bounds__(256) void k_convemb(const float* __restrict__ E, u16* __restrict__ Eb){
  int idx = blockIdx.x * 256 + threadIdx.x;        // 36 blocks -> 9216
  if (idx < 144 * 64){
    int r = idx >> 6;
    Eb[idx] = (r < NR) ? f2bf(E[idx]) : (u16)0;
  }
}

// ---------------- QKV GEMM: [4096,1024] x Wt[1024,1024]^T, bf16 MFMA ----------------
// out layout: [g = b*16+h][s][j] bf16 ; Q pre-scaled by 0.125*log2(e) (base-2 softmax)
__global__ __launch_bounds__(256) void k_qkv(const u16* __restrict__ Xb, const u16* __restrict__ Wt,
                                             const float* __restrict__ bq, const float* __restrict__ bk,
                                             const float* __restrict__ bv,
                                             u16* __restrict__ Qs, u16* __restrict__ Kb, u16* __restrict__ Vb){
  const int z = blockIdx.z;
  const u16* W = Wt + (size_t)z * 1024 * 1024;
  const float* bias = (z == 0) ? bq : (z == 1) ? bk : bv;
  u16* outp = (z == 0) ? Qs : (z == 1) ? Kb : Vb;
  const float vs = (z == 0) ? 0.125f * LOG2E : 1.0f;
  const int n0 = blockIdx.x * 128, m0 = blockIdx.y * 128;
  const int tid = threadIdx.x, w = tid >> 6, lane = tid & 63, l15 = lane & 15, quad = lane >> 4;
  const int wm = (w >> 1) * 64, wn = (w & 1) * 64;
  __shared__ __attribute__((aligned(16))) u16 As[128][40];
  __shared__ __attribute__((aligned(16))) u16 Bs[128][40];
  f32x4 acc[4][4];
  #pragma unroll
  for (int i = 0; i < 4; ++i)
    #pragma unroll
    for (int j = 0; j < 4; ++j) acc[i][j] = (f32x4){0.f,0.f,0.f,0.f};

  for (int k0 = 0; k0 < 1024; k0 += 32){
    __syncthreads();
    #pragma unroll
    for (int i = 0; i < 2; ++i){
      int c = tid + i * 256; int r = c >> 2, ch = (c & 3) * 8;
      *(short8*)&As[r][ch] = *(const short8*)(Xb + (size_t)(m0 + r) * 1024 + k0 + ch);
      *(short8*)&Bs[r][ch] = *(const short8*)(W  + (size_t)(n0 + r) * 1024 + k0 + ch);
    }
    __syncthreads();
    short8 af[4], bfr[4];
    #pragma unroll
    for (int f = 0; f < 4; ++f){
      af[f]  = *(const short8*)&As[wm + f * 16 + l15][quad * 8];
      bfr[f] = *(const short8*)&Bs[wn + f * 16 + l15][quad * 8];
    }
    #pragma unroll
    for (int i = 0; i < 4; ++i)
      #pragma unroll
      for (int j = 0; j < 4; ++j) acc[i][j] = MFMA(af[i], bfr[j], acc[i][j]);
  }
  #pragma unroll
  for (int i = 0; i < 4; ++i){
    #pragma unroll
    for (int j = 0; j < 4; ++j){
      int col = n0 + wn + j * 16 + l15;
      float bsv = bias[col];
      int hh = col >> 6, jd = col & 63;
      #pragma unroll
      for (int r = 0; r < 4; ++r){
        int row = m0 + wm + i * 16 + quad * 4 + r;
        int bb = row >> 11, s = row & 2047;
        float vv = (acc[i][j][r] + bsv) * vs;
        outp[(((size_t)(bb * 16 + hh)) * S_LEN + s) * 64 + jd] = f2bf(vv);
      }
    }
  }
}

// ---------------- transpose V: [g][s][d] -> Vt[g][d][s] ----------------
__global__ __launch_bounds__(256) void k_transv(const u16* __restrict__ Vb, u16* __restrict__ Vt){
  const int g = blockIdx.y; const int s0 = blockIdx.x * 64;
  __shared__ __attribute__((aligned(16))) u16 t[64][72];
  const int tid = threadIdx.x;
  #pragma unroll
  for (int i = 0; i < 2; ++i){
    int c = tid + i * 256; int r = c >> 3, ch = (c & 7) * 8;
    *(short8*)&t[r][ch] = *(const short8*)(Vb + ((size_t)g * S_LEN + s0 + r) * 64 + ch);
  }
  __syncthreads();
  #pragma unroll
  for (int i = 0; i < 2; ++i){
    int c = tid + i * 256; int d = c >> 3, ch = (c & 7) * 8;
    short8 vv;
    #pragma unroll
    for (int u = 0; u < 8; ++u) vv[u] = (short)t[ch + u][d];
    *(short8*)(Vt + ((size_t)g * 64 + d) * S_LEN + s0 + ch) = vv;
  }
}

// ---------------- flash attention v2: base-2 softmax, fixed m=0, tile classification ----------------
// scores already in log2 domain (Q pre-scaled by 0.125*log2e). Only 3 tiles near the
// diagonal need the per-element rel-idx gather; all others use per-row constants.
// Stores per-row l (sum 2^s) and ll (sum over k<=q-64).
__global__ __launch_bounds__(256) void k_flash(const u16* __restrict__ QS, const u16* __restrict__ KB,
                                               const u16* __restrict__ VT, const u16* __restrict__ EMBK,
                                               const float* __restrict__ mask, float* __restrict__ out,
                                               float* __restrict__ lS, float* __restrict__ llS){
  const int g = blockIdx.y; const int b = g >> 4; const int h = g & 15;
  const int q0 = blockIdx.x * 64;
  const int tid = threadIdx.x;
  const int w = tid >> 6; const int lane = tid & 63;
  const int l15 = lane & 15; const int quad = lane >> 4;
  const int wm = w * 16;

  __shared__ __attribute__((aligned(16))) u16 Ks[64][72];
  __shared__ __attribute__((aligned(16))) u16 Vs[64][72];
  __shared__ __attribute__((aligned(16))) u16 Ps[4][16][72];
  __shared__ __attribute__((aligned(16))) u16 QEb[4][16][132];   // bf16 qe per wave

  // Q A-fragments straight from global
  const u16* qptr = QS + ((size_t)g * S_LEN + q0 + wm + l15) * 64 + quad * 8;
  short8 qa0 = *(const short8*)qptr;
  short8 qa1 = *(const short8*)(qptr + 32);

  const int rqb = quad * 4;            // this lane's C-row base within the wave's 16 rows

  // qe = Q @ emb_k^T (this wave's 16 rows; cols 0..128), bf16 into wave-private LDS
  #pragma unroll
  for (int fn = 0; fn < 9; ++fn){
    const u16* ep = EMBK + (fn * 16 + l15) * 64 + quad * 8;
    short8 eb0 = *(const short8*)ep;
    short8 eb1 = *(const short8*)(ep + 32);
    f32x4 c = (f32x4){0.f,0.f,0.f,0.f};
    c = MFMA(qa0, eb0, c);
    c = MFMA(qa1, eb1, c);
    int col = fn * 16 + l15;
    if (col < NR){
      #pragma unroll
      for (int r = 0; r < 4; ++r) QEb[w][rqb + r][col] = f2bf(c[r]);
    }
  }
  __syncthreads();   // also covers QEb visibility

  float qeR[4], qeL[4];
  #pragma unroll
  for (int r = 0; r < 4; ++r){
    qeR[r] = bf2f(QEb[w][rqb + r][0]);
    qeL[r] = bf2f(QEb[w][rqb + r][128]);
  }

  f32x4 o[4];
  #pragma unroll
  for (int f = 0; f < 4; ++f) o[f] = (f32x4){0.f,0.f,0.f,0.f};
  float l_lane[4] = {0.f,0.f,0.f,0.f}, ll_lane[4] = {0.f,0.f,0.f,0.f};

  for (int kt = 0; kt < S_LEN; kt += 64){
    __syncthreads();
    #pragma unroll
    for (int i = 0; i < 2; ++i){
      int c = tid + i * 256; int row = c >> 3, ch = (c & 7) * 8;
      *(short8*)&Ks[row][ch] = *(const short8*)(KB + ((size_t)g * S_LEN + kt + row) * 64 + ch);
      *(short8*)&Vs[row][ch] = *(const short8*)(VT + ((size_t)g * 64 + row) * S_LEN + kt + ch);
    }
    __syncthreads();

    // scores (log2 domain)
    f32x4 sc[4];
    #pragma unroll
    for (int fn = 0; fn < 4; ++fn){
      short8 kb0 = *(const short8*)&Ks[fn * 16 + l15][quad * 8];
      short8 kb1 = *(const short8*)&Ks[fn * 16 + l15][32 + quad * 8];
      f32x4 c = (f32x4){0.f,0.f,0.f,0.f};
      c = MFMA(qa0, kb0, c);
      c = MFMA(qa1, kb1, c);
      sc[fn] = c;
    }

    if (kt <= q0 - 128){
      // fully left-clamped: ridx=128 for all; contributes to ll
      #pragma unroll
      for (int fn = 0; fn < 4; ++fn){
        float mv = mask[b * S_LEN + kt + fn * 16 + l15] * LOG2E;
        #pragma unroll
        for (int r = 0; r < 4; ++r){
          float p = exp2f(sc[fn][r] + qeL[r] + mv);
          l_lane[r] += p; ll_lane[r] += p;
          sc[fn][r] = p;
        }
      }
    } else if (kt >= q0 + 128){
      // fully right-clamped: ridx=0
      #pragma unroll
      for (int fn = 0; fn < 4; ++fn){
        float mv = mask[b * S_LEN + kt + fn * 16 + l15] * LOG2E;
        #pragma unroll
        for (int r = 0; r < 4; ++r){
          float p = exp2f(sc[fn][r] + qeR[r] + mv);
          l_lane[r] += p;
          sc[fn][r] = p;
        }
      }
    } else {
      // mixed: per-element gather
      #pragma unroll
      for (int fn = 0; fn < 4; ++fn){
        int kg = kt + fn * 16 + l15;
        float mv = mask[b * S_LEN + kg] * LOG2E;
        #pragma unroll
        for (int r = 0; r < 4; ++r){
          int dq = (q0 + wm + rqb + r) - kg + 64;
          int ridx = min(max(dq, 0), 128);
          float p = exp2f(sc[fn][r] + bf2f(QEb[w][rqb + r][ridx]) + mv);
          l_lane[r] += p;
          ll_lane[r] += (ridx == 128) ? p : 0.f;
          sc[fn][r] = p;
        }
      }
    }

    // P -> LDS (wave-private region)
    #pragma unroll
    for (int fn = 0; fn < 4; ++fn)
      #pragma unroll
      for (int r = 0; r < 4; ++r) Ps[w][rqb + r][fn * 16 + l15] = f2bf(sc[fn][r]);
    // PV
    #pragma unroll
    for (int ks = 0; ks < 2; ++ks){
      short8 pa = *(const short8*)&Ps[w][l15][ks * 32 + quad * 8];
      #pragma unroll
      for (int fd = 0; fd < 4; ++fd){
        short8 vb = *(const short8*)&Vs[fd * 16 + l15][ks * 32 + quad * 8];
        o[fd] = MFMA(pa, vb, o[fd]);
      }
    }
  }

  // single final reduction across the 16 lanes sharing each row
  #pragma unroll
  for (int st = 1; st < 16; st <<= 1)
    #pragma unroll
    for (int r = 0; r < 4; ++r){
      l_lane[r]  += __shfl_xor(l_lane[r], st, 64);
      ll_lane[r] += __shfl_xor(ll_lane[r], st, 64);
    }

  float inv[4];
  #pragma unroll
  for (int r = 0; r < 4; ++r) inv[r] = 1.f / l_lane[r];
  #pragma unroll
  for (int fd = 0; fd < 4; ++fd)
    #pragma unroll
    for (int r = 0; r < 4; ++r){
      int row = q0 + wm + rqb + r;
      out[((size_t)(b * S_LEN + row)) * DMODEL + h * 64 + fd * 16 + l15] = o[fd][r] * inv[r];
    }
  if (l15 == 0){
    #pragma unroll
    for (int r = 0; r < 4; ++r){
      int idx = g * S_LEN + q0 + wm + rqb + r;
      lS[idx] = l_lane[r]; llS[idx] = ll_lane[r];
    }
  }
}

// ---------------- band v2 (MFMA): rel_v contribution via diagonal-band GEMM ----------------
__global__ __launch_bounds__(256) void k_band2(const u16* __restrict__ QS, const u16* __restrict__ KB,
                                               const u16* __restrict__ EMBK, const float* __restrict__ embv,
                                               const float* __restrict__ mask,
                                               const float* __restrict__ lS, const float* __restrict__ llS,
                                               float* __restrict__ out){
  const int g = blockIdx.y; const int b = g >> 4; const int h = g & 15;
  const int q0 = blockIdx.x * 64;
  const int tid = threadIdx.x;
  const int w = tid >> 6; const int lane = tid & 63;
  const int l15 = lane & 15; const int quad = lane >> 4;
  const int wm = w * 16;

  __shared__ union {
    __attribute__((aligned(16))) u16 Ks[192][72];   // K rows q0-63 .. q0+128 (c=0..191, k=q0-63+c)
    __attribute__((aligned(16))) u16 Evs[64][136];  // Evs[d][t] = emb_v[127-t][d], t<=126; else 0
  } uKE;
  __shared__ __attribute__((aligned(16))) u16 Ps[64][136];   // Pd[row][t]
  __shared__ u16 QEs[64][128];                               // qe[row][ridx-1], ridx=1..128

  // zero Ps (tail cols / out-of-band stay 0)
  for (int i = tid; i < 64 * 136 / 2; i += 256) ((uint32_t*)Ps)[i] = 0u;

  // stage K band range: c=0..191 -> k=q0-63+c, zero-fill OOB
  #pragma unroll
  for (int i = 0; i < 6; ++i){
    int c = tid + i * 256; int row = c >> 3, ch = (c & 7) * 8;
    int k = q0 - 63 + row;
    short8 vv;
    if (k >= 0 && k < S_LEN) vv = *(const short8*)(KB + ((size_t)g * S_LEN + k) * 64 + ch);
    else vv = (short8){0,0,0,0,0,0,0,0};
    *(short8*)&uKE.Ks[row][ch] = vv;
  }

  // Q A-fragments (rows wm+l15)
  const u16* qptr = QS + ((size_t)g * S_LEN + q0 + wm + l15) * 64 + quad * 8;
  short8 qa0 = *(const short8*)qptr;
  short8 qa1 = *(const short8*)(qptr + 32);

  __syncthreads();

  // qe = Q @ emb_k^T for this wave's rows; store bf16 at QEs[row][e-1], e=1..128
  #pragma unroll
  for (int fn = 0; fn < 9; ++fn){
    const u16* ep = EMBK + (fn * 16 + l15) * 64 + quad * 8;
    short8 eb0 = *(const short8*)ep;
    short8 eb1 = *(const short8*)(ep + 32);
    f32x4 c = (f32x4){0.f,0.f,0.f,0.f};
    c = MFMA(qa0, eb0, c);
    c = MFMA(qa1, eb1, c);
    int e = fn * 16 + l15;
    if (e >= 1 && e <= 128){
      #pragma unroll
      for (int r = 0; r < 4; ++r) QEs[wm + quad * 4 + r][e - 1] = f2bf(c[r]);
    }
  }

  // band scores: S = Q @ K^T over 192 cols
  f32x4 sc[12];
  #pragma unroll
  for (int cf = 0; cf < 12; ++cf){
    short8 kb0 = *(const short8*)&uKE.Ks[cf * 16 + l15][quad * 8];
    short8 kb1 = *(const short8*)&uKE.Ks[cf * 16 + l15][32 + quad * 8];
    f32x4 c = (f32x4){0.f,0.f,0.f,0.f};
    c = MFMA(qa0, kb0, c);
    c = MFMA(qa1, kb1, c);
    sc[cf] = c;
  }

  __syncthreads();   // Ks reads done; safe to overwrite with Evs

  // build Evs (union with Ks): Evs[d][t] = emb_v[127-t][d] for t<=126, else 0
  #pragma unroll
  for (int it = 0; it < 34; ++it){
    int t = (tid >> 6) + it * 4;
    int d = tid & 63;
    float v = (t <= 126) ? embv[(size_t)(127 - t) * 64 + d] : 0.f;
    uKE.Evs[d][t] = f2bf(v);
  }

  // per-row softmax stats from flash (m=0, base-2)
  float invl[4], tl[4];
  #pragma unroll
  for (int r = 0; r < 4; ++r){
    int idx = g * S_LEN + q0 + wm + quad * 4 + r;
    invl[r] = 1.f / lS[idx];
    tl[r]   = llS[idx] * invl[r];
  }

  // p = 2^(s + qe + mask)/l ; scatter band into Ps[row][t], t=c-rq
  float rs[4] = {0.f,0.f,0.f,0.f};
  #pragma unroll
  for (int cf = 0; cf < 12; ++cf){
    int c = cf * 16 + l15;
    int k = q0 - 63 + c;
    int kcl = min(max(k, 0), S_LEN - 1);
    float mv = mask[b * S_LEN + kcl] * LOG2E;
    #pragma unroll
    for (int r = 0; r < 4; ++r){
      int rq = wm + quad * 4 + r;
      int t = c - rq;
      bool valid = (t >= 0) && (t <= 126) && (k >= 0) && (k < S_LEN);
      if (valid){
        float s = sc[cf][r] + bf2f(QEs[rq][126 - t]) + mv;
        float p = exp2f(s) * invl[r];
        Ps[rq][t] = f2bf(p);
        rs[r] += p;
      }
    }
  }
  // row band-sums across l15 lanes
  #pragma unroll
  for (int st = 1; st < 16; st <<= 1)
    #pragma unroll
    for (int r = 0; r < 4; ++r) rs[r] += __shfl_xor(rs[r], st, 64);

  __syncthreads();   // Ps + Evs ready

  // rv = Pd @ Ev'
  f32x4 o[4];
  #pragma unroll
  for (int f = 0; f < 4; ++f) o[f] = (f32x4){0.f,0.f,0.f,0.f};
  #pragma unroll
  for (int kb = 0; kb < 4; ++kb){
    short8 pa = *(const short8*)&Ps[wm + l15][kb * 32 + quad * 8];
    #pragma unroll
    for (int fd = 0; fd < 4; ++fd){
      short8 vb = *(const short8*)&uKE.Evs[fd * 16 + l15][kb * 32 + quad * 8];
      o[fd] = MFMA(pa, vb, o[fd]);
    }
  }

  // epilogue: add tails and accumulate into out
  #pragma unroll
  for (int fd = 0; fd < 4; ++fd){
    int dim = fd * 16 + l15;
    float evL = embv[(size_t)128 * 64 + dim];   // ridx=128 (k <= q-64)
    float evR = embv[dim];                      // ridx=0   (k >= q+64)
    #pragma unroll
    for (int r = 0; r < 4; ++r){
      float trr = 1.f - tl[r] - rs[r];
      float add = o[fd][r] + tl[r] * evL + trr * evR;
      int row = q0 + wm + quad * 4 + r;
      out[((size_t)(b * S_LEN + row)) * DMODEL + h * 64 + dim] += add;
    }
  }
}

extern "C" void kernel_launch(void* const* d_in, const int* in_sizes, int n_in,
                              void* d_out, int out_size, void* d_ws, size_t ws_size,
                              hipStream_t stream){
  const float* X    = (const float*)d_in[0];
  const float* mask = (const float*)d_in[1];
  const float* Wq   = (const float*)d_in[2];
  const float* bq   = (const float*)d_in[3];
  const float* Wk   = (const float*)d_in[4];
  const float* bk   = (const float*)d_in[5];
  const float* Wv   = (const float*)d_in[6];
  const float* bv   = (const float*)d_in[7];
  const float* embk = (const float*)d_in[8];
  const float* embv = (const float*)d_in[9];
  float* out = (float*)d_out;
  char* ws = (char*)d_ws;

  u16* XB  = (u16*)(ws + 0);            // 8,388,608
  u16* WT  = (u16*)(ws + 8388608);      // 6,291,456
  u16* EKB = (u16*)(ws + 14680064);     // 18,432
  u16* QS  = (u16*)(ws + 14698496);     // 8,388,608
  u16* KB  = (u16*)(ws + 23087104);     // 8,388,608
  u16* VB  = (u16*)(ws + 31475712);     // 8,388,608
  u16* VT  = (u16*)(ws + 39864320);     // 8,388,608
  float* LS  = (float*)(ws + 48252928); // 262,144
  float* LLS = (float*)(ws + 48515072); // 262,144  (end 48,777,216)

  k_convx  <<<4096, 256, 0, stream>>>(X, XB);
  k_transw <<<dim3(16, 16, 3), 256, 0, stream>>>(Wq, Wk, Wv, WT);
  k_convemb<<<36, 256, 0, stream>>>(embk, EKB);
  k_qkv    <<<dim3(8, 32, 3), 256, 0, stream>>>(XB, WT, bq, bk, bv, QS, KB, VB);
  k_transv <<<dim3(32, 32), 256, 0, stream>>>(VB, VT);
  k_flash  <<<dim3(32, 32), 256, 0, stream>>>(QS, KB, VT, EKB, mask, out, LS, LLS);
  k_band2  <<<dim3(32, 32), 256, 0, stream>>>(QS, KB, EKB, embv, mask, LS, LLS, out);
}

// Round 4
// 271.540 us; speedup vs baseline: 2.7921x; 1.1167x over previous
//
#include <hip/hip_runtime.h>
#include <stdint.h>

typedef unsigned short u16;
typedef __attribute__((ext_vector_type(8))) short short8;
typedef __attribute__((ext_vector_type(4))) float f32x4;
typedef __attribute__((ext_vector_type(4))) unsigned short u16x4;

#define S_LEN 2048
#define NH 16
#define DMODEL 1024
#define NR 129
#define LOG2E 1.44269504f

#define MFMA(a,b,c) __builtin_amdgcn_mfma_f32_16x16x32_bf16((a),(b),(c),0,0,0)

__device__ __forceinline__ u16 f2bf(float f){            // RTNE (for Q/K/V/emb)
  uint32_t u = __float_as_uint(f);
  u += 0x7fff + ((u >> 16) & 1);
  return (u16)(u >> 16);
}
__device__ __forceinline__ u16 f2bfa(float f){           // RTNA (cheap, for p>=0)
  return (u16)((__float_as_uint(f) + 0x8000u) >> 16);
}
__device__ __forceinline__ float bf2f(u16 h){ return __uint_as_float(((uint32_t)h) << 16); }

// ---------------- prep: convx + transw + convemb + mask*log2e, one launch ----------------
// blocks: [0,4096) convx | [4096,4864) transw | [4864,4900) convemb | [4900,4916) maskL
__global__ __launch_bounds__(256) void k_prep(const float* __restrict__ X,
                                              const float* __restrict__ Wq, const float* __restrict__ Wk,
                                              const float* __restrict__ Wv, const float* __restrict__ Wemb,
                                              const float* __restrict__ mask,
                                              u16* __restrict__ Xb, u16* __restrict__ Wt,
                                              u16* __restrict__ Eb, float* __restrict__ maskL){
  const int bid = blockIdx.x, tid = threadIdx.x;
  if (bid < 4096){
    int i = bid * 256 + tid;
    const float4* xp = (const float4*)X;
    float4 v = xp[i];
    u16x4 o; o.x = f2bf(v.x); o.y = f2bf(v.y); o.z = f2bf(v.z); o.w = f2bf(v.w);
    *(u16x4*)(Xb + (size_t)i * 4) = o;
  } else if (bid < 4864){
    int b2 = bid - 4096;
    int z = b2 >> 8;
    const float* W = (z == 0) ? Wq : (z == 1) ? Wk : Wv;
    u16* Ot = Wt + (size_t)z * 1024 * 1024;
    __shared__ float t[64][65];
    int k0 = ((b2 >> 4) & 15) * 64, n0 = (b2 & 15) * 64;
    int c = tid & 63, r0 = (tid >> 6) * 16;
    #pragma unroll
    for (int i = 0; i < 16; ++i) t[r0 + i][c] = W[(size_t)(k0 + r0 + i) * 1024 + n0 + c];
    __syncthreads();
    #pragma unroll
    for (int i = 0; i < 16; ++i) Ot[(size_t)(n0 + r0 + i) * 1024 + k0 + c] = f2bf(t[c][r0 + i]);
  } else if (bid < 4900){
    int idx = (bid - 4864) * 256 + tid;
    if (idx < 144 * 64){
      int r = idx >> 6;
      Eb[idx] = (r < NR) ? f2bf(Wemb[idx]) : (u16)0;
    }
  } else {
    int idx = (bid - 4900) * 256 + tid;   // 4096 mask elements
    maskL[idx] = mask[idx] * LOG2E;
  }
}

// ---------------- QKV GEMM: [4096,1024] x Wt[1024,1024]^T, bf16 MFMA ----------------
// out layout: [g = b*16+h][s][j] bf16 ; Q pre-scaled by 0.125*log2(e) (base-2 softmax)
__global__ __launch_bounds__(256) void k_qkv(const u16* __restrict__ Xb, const u16* __restrict__ Wt,
                                             const float* __restrict__ bq, const float* __restrict__ bk,
                                             const float* __restrict__ bv,
                                             u16* __restrict__ Qs, u16* __restrict__ Kb, u16* __restrict__ Vb){
  const int z = blockIdx.z;
  const u16* W = Wt + (size_t)z * 1024 * 1024;
  const float* bias = (z == 0) ? bq : (z == 1) ? bk : bv;
  u16* outp = (z == 0) ? Qs : (z == 1) ? Kb : Vb;
  const float vs = (z == 0) ? 0.125f * LOG2E : 1.0f;
  const int n0 = blockIdx.x * 128, m0 = blockIdx.y * 128;
  const int tid = threadIdx.x, w = tid >> 6, lane = tid & 63, l15 = lane & 15, quad = lane >> 4;
  const int wm = (w >> 1) * 64, wn = (w & 1) * 64;
  __shared__ __attribute__((aligned(16))) u16 As[128][40];
  __shared__ __attribute__((aligned(16))) u16 Bs[128][40];
  f32x4 acc[4][4];
  #pragma unroll
  for (int i = 0; i < 4; ++i)
    #pragma unroll
    for (int j = 0; j < 4; ++j) acc[i][j] = (f32x4){0.f,0.f,0.f,0.f};

  for (int k0 = 0; k0 < 1024; k0 += 32){
    __syncthreads();
    #pragma unroll
    for (int i = 0; i < 2; ++i){
      int c = tid + i * 256; int r = c >> 2, ch = (c & 3) * 8;
      *(short8*)&As[r][ch] = *(const short8*)(Xb + (size_t)(m0 + r) * 1024 + k0 + ch);
      *(short8*)&Bs[r][ch] = *(const short8*)(W  + (size_t)(n0 + r) * 1024 + k0 + ch);
    }
    __syncthreads();
    short8 af[4], bfr[4];
    #pragma unroll
    for (int f = 0; f < 4; ++f){
      af[f]  = *(const short8*)&As[wm + f * 16 + l15][quad * 8];
      bfr[f] = *(const short8*)&Bs[wn + f * 16 + l15][quad * 8];
    }
    #pragma unroll
    for (int i = 0; i < 4; ++i)
      #pragma unroll
      for (int j = 0; j < 4; ++j) acc[i][j] = MFMA(af[i], bfr[j], acc[i][j]);
  }
  #pragma unroll
  for (int i = 0; i < 4; ++i){
    #pragma unroll
    for (int j = 0; j < 4; ++j){
      int col = n0 + wn + j * 16 + l15;
      float bsv = bias[col];
      int hh = col >> 6, jd = col & 63;
      #pragma unroll
      for (int r = 0; r < 4; ++r){
        int row = m0 + wm + i * 16 + quad * 4 + r;
        int bb = row >> 11, s = row & 2047;
        float vv = (acc[i][j][r] + bsv) * vs;
        outp[(((size_t)(bb * 16 + hh)) * S_LEN + s) * 64 + jd] = f2bf(vv);
      }
    }
  }
}

// ---------------- transpose V: [g][s][d] -> Vt[g][d][s] ----------------
__global__ __launch_bounds__(256) void k_transv(const u16* __restrict__ Vb, u16* __restrict__ Vt){
  const int g = blockIdx.y; const int s0 = blockIdx.x * 64;
  __shared__ __attribute__((aligned(16))) u16 t[64][72];
  const int tid = threadIdx.x;
  #pragma unroll
  for (int i = 0; i < 2; ++i){
    int c = tid + i * 256; int r = c >> 3, ch = (c & 7) * 8;
    *(short8*)&t[r][ch] = *(const short8*)(Vb + ((size_t)g * S_LEN + s0 + r) * 64 + ch);
  }
  __syncthreads();
  #pragma unroll
  for (int i = 0; i < 2; ++i){
    int c = tid + i * 256; int d = c >> 3, ch = (c & 7) * 8;
    short8 vv;
    #pragma unroll
    for (int u = 0; u < 8; ++u) vv[u] = (short)t[ch + u][d];
    *(short8*)(Vt + ((size_t)g * 64 + d) * S_LEN + s0 + ch) = vv;
  }
}

// ---------------- fused flash + rel_v band, base-2 softmax, fixed m=0 ----------------
// Main loop: O_main = sum_k 2^(qk + qe + maskL) * V (raw, unnormalized), accumulating
// l (row sum). Mixed tiles also capture band p into Psb[row][t] (t = k - q + 63) and
// the band row-sum; ll (left-clamp sum) = snapshot of l after the last fully-left tile
// plus predicated adds in the left-mixed tile. Tail: rv = Psb @ Ev', fused epilogue
// adds tails and normalizes once.
__global__ __launch_bounds__(256) void k_flash(const u16* __restrict__ QS, const u16* __restrict__ KB,
                                               const u16* __restrict__ VT, const u16* __restrict__ EMBK,
                                               const float* __restrict__ maskL, const float* __restrict__ embv,
                                               float* __restrict__ out){
  const int g = blockIdx.y; const int b = g >> 4; const int h = g & 15;
  const int q0 = blockIdx.x * 64;
  const int tid = threadIdx.x;
  const int w = tid >> 6; const int lane = tid & 63;
  const int l15 = lane & 15; const int quad = lane >> 4;
  const int wm = w * 16;
  const int rqb = quad * 4;

  __shared__ union UKE {
    struct {
      __attribute__((aligned(16))) u16 Ks[64][72];
      __attribute__((aligned(16))) u16 Vs[64][72];
    } s;
    __attribute__((aligned(16))) u16 Evs[64][136];   // Evs[d][t] = emb_v[127-t][d]
  } uu;                                              // 18,432 B
  __shared__ __attribute__((aligned(16))) u16 Ps[4][16][72];    // 9,216
  __shared__ __attribute__((aligned(16))) u16 QEb[4][16][132];  // 16,896
  __shared__ __attribute__((aligned(16))) u16 Psb[64][136];     // 17,408  (total 61,952)

  // zero Psb
  {
    short8 z8 = (short8){0,0,0,0,0,0,0,0};
    for (int i = tid; i < 64 * 136 / 8; i += 256) ((short8*)Psb)[i] = z8;
  }

  // Q A-fragments straight from global
  const u16* qptr = QS + ((size_t)g * S_LEN + q0 + wm + l15) * 64 + quad * 8;
  short8 qa0 = *(const short8*)qptr;
  short8 qa1 = *(const short8*)(qptr + 32);

  // qe = Q @ emb_k^T (this wave's 16 rows; cols 0..128), bf16 into wave-private LDS
  #pragma unroll
  for (int fn = 0; fn < 9; ++fn){
    const u16* ep = EMBK + (fn * 16 + l15) * 64 + quad * 8;
    short8 eb0 = *(const short8*)ep;
    short8 eb1 = *(const short8*)(ep + 32);
    f32x4 c = (f32x4){0.f,0.f,0.f,0.f};
    c = MFMA(qa0, eb0, c);
    c = MFMA(qa1, eb1, c);
    int col = fn * 16 + l15;
    if (col < NR){
      #pragma unroll
      for (int r = 0; r < 4; ++r) QEb[w][rqb + r][col] = f2bf(c[r]);
    }
  }
  __syncthreads();   // QEb + Psb-zero visible

  float qeR[4], qeL[4];
  #pragma unroll
  for (int r = 0; r < 4; ++r){
    qeR[r] = bf2f(QEb[w][rqb + r][0]);
    qeL[r] = bf2f(QEb[w][rqb + r][128]);
  }

  f32x4 o[4];
  #pragma unroll
  for (int f = 0; f < 4; ++f) o[f] = (f32x4){0.f,0.f,0.f,0.f};
  float l_lane[4] = {0.f,0.f,0.f,0.f};
  float ll0[4]    = {0.f,0.f,0.f,0.f};   // snapshot after last fully-left tile
  float ll_mx[4]  = {0.f,0.f,0.f,0.f};   // clamped-left contributions from mixed tiles
  float rsb[4]    = {0.f,0.f,0.f,0.f};   // band row-sum (raw)

  for (int kt = 0; kt < S_LEN; kt += 64){
    __syncthreads();
    #pragma unroll
    for (int i = 0; i < 2; ++i){
      int c = tid + i * 256; int row = c >> 3, ch = (c & 7) * 8;
      *(short8*)&uu.s.Ks[row][ch] = *(const short8*)(KB + ((size_t)g * S_LEN + kt + row) * 64 + ch);
      *(short8*)&uu.s.Vs[row][ch] = *(const short8*)(VT + ((size_t)g * 64 + row) * S_LEN + kt + ch);
    }
    __syncthreads();

    // mask (pre-scaled by log2e)
    float mvl[4];
    #pragma unroll
    for (int fn = 0; fn < 4; ++fn) mvl[fn] = maskL[b * S_LEN + kt + fn * 16 + l15];

    // scores (log2 domain)
    f32x4 sc[4];
    #pragma unroll
    for (int fn = 0; fn < 4; ++fn){
      short8 kb0 = *(const short8*)&uu.s.Ks[fn * 16 + l15][quad * 8];
      short8 kb1 = *(const short8*)&uu.s.Ks[fn * 16 + l15][32 + quad * 8];
      f32x4 c = (f32x4){0.f,0.f,0.f,0.f};
      c = MFMA(qa0, kb0, c);
      c = MFMA(qa1, kb1, c);
      sc[fn] = c;
    }

    if (kt <= q0 - 128){
      // fully left-clamped: ridx=128
      #pragma unroll
      for (int fn = 0; fn < 4; ++fn)
        #pragma unroll
        for (int r = 0; r < 4; ++r){
          float p = exp2f(sc[fn][r] + qeL[r] + mvl[fn]);
          l_lane[r] += p;
          sc[fn][r] = p;
        }
    } else if (kt >= q0 + 128){
      // fully right-clamped: ridx=0
      #pragma unroll
      for (int fn = 0; fn < 4; ++fn)
        #pragma unroll
        for (int r = 0; r < 4; ++r){
          float p = exp2f(sc[fn][r] + qeR[r] + mvl[fn]);
          l_lane[r] += p;
          sc[fn][r] = p;
        }
    } else {
      // mixed: per-element gather + band capture
      #pragma unroll
      for (int fn = 0; fn < 4; ++fn){
        int kg = kt + fn * 16 + l15;
        #pragma unroll
        for (int r = 0; r < 4; ++r){
          int lr = wm + rqb + r;
          int dq = (q0 + lr) - kg + 64;       // unclamped rel idx
          int ridx = min(max(dq, 0), 128);
          float p = exp2f(sc[fn][r] + bf2f(QEb[w][rqb + r][ridx]) + mvl[fn]);
          l_lane[r] += p;
          ll_mx[r] += (dq >= 128) ? p : 0.f;
          if (dq >= 1 && dq <= 127){          // band element: t = 127 - dq
            Psb[lr][127 - dq] = f2bfa(p);
            rsb[r] += p;
          }
          sc[fn][r] = p;
        }
      }
    }

    // P -> LDS (wave-private region)
    #pragma unroll
    for (int fn = 0; fn < 4; ++fn)
      #pragma unroll
      for (int r = 0; r < 4; ++r) Ps[w][rqb + r][fn * 16 + l15] = f2bfa(sc[fn][r]);
    // PV
    #pragma unroll
    for (int ks = 0; ks < 2; ++ks){
      short8 pa = *(const short8*)&Ps[w][l15][ks * 32 + quad * 8];
      #pragma unroll
      for (int fd = 0; fd < 4; ++fd){
        short8 vb = *(const short8*)&uu.s.Vs[fd * 16 + l15][ks * 32 + quad * 8];
        o[fd] = MFMA(pa, vb, o[fd]);
      }
    }

    if (kt == q0 - 128){
      #pragma unroll
      for (int r = 0; r < 4; ++r) ll0[r] = l_lane[r];
    }
  }

  // ---- band tail ----
  __syncthreads();   // all Ks/Vs reads done; Psb writes complete
  // build Evs in the union region: Evs[d][t] = emb_v[127-t][d] (t<=126), else 0
  {
    int d = tid & 63, t4 = tid >> 6;
    #pragma unroll
    for (int it = 0; it < 34; ++it){
      int t = t4 + it * 4;
      float v = (t <= 126) ? embv[(size_t)(127 - t) * 64 + d] : 0.f;
      uu.Evs[d][t] = f2bf(v);
    }
  }
  __syncthreads();

  f32x4 ob[4];
  #pragma unroll
  for (int f = 0; f < 4; ++f) ob[f] = (f32x4){0.f,0.f,0.f,0.f};
  #pragma unroll
  for (int kb = 0; kb < 4; ++kb){
    short8 pa = *(const short8*)&Psb[wm + l15][kb * 32 + quad * 8];
    #pragma unroll
    for (int fd = 0; fd < 4; ++fd){
      short8 vb = *(const short8*)&uu.Evs[fd * 16 + l15][kb * 32 + quad * 8];
      ob[fd] = MFMA(pa, vb, ob[fd]);
    }
  }

  // final reductions across the 16 lanes sharing each row
  float ll[4];
  #pragma unroll
  for (int r = 0; r < 4; ++r) ll[r] = ll0[r] + ll_mx[r];
  #pragma unroll
  for (int st = 1; st < 16; st <<= 1)
    #pragma unroll
    for (int r = 0; r < 4; ++r){
      l_lane[r] += __shfl_xor(l_lane[r], st, 64);
      ll[r]     += __shfl_xor(ll[r], st, 64);
      rsb[r]    += __shfl_xor(rsb[r], st, 64);
    }

  float inv[4], tl[4], trr[4];
  #pragma unroll
  for (int r = 0; r < 4; ++r){
    inv[r] = 1.f / l_lane[r];
    tl[r]  = ll[r] * inv[r];
    trr[r] = 1.f - tl[r] - rsb[r] * inv[r];
  }

  #pragma unroll
  for (int fd = 0; fd < 4; ++fd){
    int dim = fd * 16 + l15;
    float evL = embv[(size_t)128 * 64 + dim];   // ridx=128 (k <= q-64)
    float evR = embv[dim];                      // ridx=0   (k >= q+64)
    #pragma unroll
    for (int r = 0; r < 4; ++r){
      int row = q0 + wm + rqb + r;
      float val = (o[fd][r] + ob[fd][r]) * inv[r] + tl[r] * evL + trr[r] * evR;
      out[((size_t)(b * S_LEN + row)) * DMODEL + h * 64 + dim] = val;
    }
  }
}

extern "C" void kernel_launch(void* const* d_in, const int* in_sizes, int n_in,
                              void* d_out, int out_size, void* d_ws, size_t ws_size,
                              hipStream_t stream){
  const float* X    = (const float*)d_in[0];
  const float* mask = (const float*)d_in[1];
  const float* Wq   = (const float*)d_in[2];
  const float* bq   = (const float*)d_in[3];
  const float* Wk   = (const float*)d_in[4];
  const float* bk   = (const float*)d_in[5];
  const float* Wv   = (const float*)d_in[6];
  const float* bv   = (const float*)d_in[7];
  const float* embk = (const float*)d_in[8];
  const float* embv = (const float*)d_in[9];
  float* out = (float*)d_out;
  char* ws = (char*)d_ws;

  u16* XB   = (u16*)(ws + 0);            // 8,388,608
  u16* WT   = (u16*)(ws + 8388608);      // 6,291,456
  u16* EKB  = (u16*)(ws + 14680064);     // 18,432
  u16* QS   = (u16*)(ws + 14698496);     // 8,388,608
  u16* KB   = (u16*)(ws + 23087104);     // 8,388,608
  u16* VB   = (u16*)(ws + 31475712);     // 8,388,608
  u16* VT   = (u16*)(ws + 39864320);     // 8,388,608
  float* MSL = (float*)(ws + 48252928);  // 16,384  (end 48,269,312)

  k_prep   <<<4916, 256, 0, stream>>>(X, Wq, Wk, Wv, embk, mask, XB, WT, EKB, MSL);
  k_qkv    <<<dim3(8, 32, 3), 256, 0, stream>>>(XB, WT, bq, bk, bv, QS, KB, VB);
  k_transv <<<dim3(32, 32), 256, 0, stream>>>(VB, VT);
  k_flash  <<<dim3(32, 32), 256, 0, stream>>>(QS, KB, VT, EKB, MSL, embv, out);
}